// Round 1
// baseline (109.757 us; speedup 1.0000x reference)
//
#include <hip/hip_runtime.h>

#define G_ 20000
#define W_ 8
#define K_ 16
#define T_ 1500
#define B_ 256
#define D_ 2
#define GPB 16   // groups per block; G_ % GPB == 0 (20000/16 = 1250 blocks)

__device__ __forceinline__ float selu_f(float x) {
    const float scale = 1.0507009873554805f;
    const float alpha = 1.6732632423543772f;
    // negative branch: scale*alpha*(exp(x)-1); positive: scale*x
    float neg = scale * alpha * (__expf(x) - 1.0f);
    return x > 0.0f ? scale * x : neg;
}

// feat (B,T) -> featT (T,B) so the main kernel's gather is lane-coalesced.
__global__ void transpose_feat(const float* __restrict__ feat,
                               float* __restrict__ featT) {
    __shared__ float tile[32][33];
    int t0 = blockIdx.x * 32;
    int b0 = blockIdx.y * 32;
    int tx = threadIdx.x, ty = threadIdx.y;  // block (32,8)
    #pragma unroll
    for (int i = 0; i < 32; i += 8) {
        int bb = b0 + ty + i, tt = t0 + tx;
        if (bb < B_ && tt < T_) tile[ty + i][tx] = feat[bb * T_ + tt];
    }
    __syncthreads();
    #pragma unroll
    for (int i = 0; i < 32; i += 8) {
        int tt = t0 + ty + i, bb = b0 + tx;
        if (tt < T_ && bb < B_) featT[tt * B_ + bb] = tile[tx][ty + i];
    }
}

// One block = 256 threads (thread = batch row b), GPB consecutive groups.
// Weight/index addresses are block-uniform -> compiler emits s_load (scalar
// cache broadcast); per-thread state stays in ~60 VGPRs.
template<bool TRANSPOSED>
__global__ __launch_bounds__(256) void decoder_kernel(
    const float* __restrict__ featsrc,   // featT (T,B) if TRANSPOSED else feat (B,T)
    const int*   __restrict__ tf_idx,    // (G,K)
    const float* __restrict__ W1,        // (G,W,K)
    const float* __restrict__ b1,        // (G,W)
    const float* __restrict__ Wm,        // (D,G,W,W)
    const float* __restrict__ bm,        // (D,G,W)
    const float* __restrict__ Wf,        // (G,W)
    const float* __restrict__ bf,        // (G,)
    float* __restrict__ out)             // (B,G)
{
    const int b  = threadIdx.x;
    const int g0 = blockIdx.x * GPB;
    float res[GPB];

    #pragma unroll
    for (int gi = 0; gi < GPB; ++gi) {
        const int g = g0 + gi;

        // gather xg[b, g, k] = features[b, tf_idx[g,k]]
        float xg[K_];
        #pragma unroll
        for (int k = 0; k < K_; ++k) {
            int t = tf_idx[g * K_ + k];                       // uniform -> s_load
            xg[k] = TRANSPOSED ? featsrc[t * B_ + b]          // coalesced
                               : featsrc[b * T_ + t];         // fallback
        }

        // layer 1: h[w] = selu(sum_k xg[k] * W1[g,w,k] + b1[g,w])
        float h[W_];
        #pragma unroll
        for (int w = 0; w < W_; ++w) {
            float acc = b1[g * W_ + w];
            #pragma unroll
            for (int k = 0; k < K_; ++k)
                acc = fmaf(xg[k], W1[(g * W_ + w) * K_ + k], acc);
            h[w] = selu_f(acc);
        }

        // D mid layers: h[v] = selu(sum_w h[w] * Wm[d,g,v,w] + bm[d,g,v])
        #pragma unroll
        for (int d = 0; d < D_; ++d) {
            const float* wmd = Wm + ((size_t)d * G_ + g) * (W_ * W_);
            const float* bmd = bm + ((size_t)d * G_ + g) * W_;
            float h2[W_];
            #pragma unroll
            for (int v = 0; v < W_; ++v) {
                float acc = bmd[v];
                #pragma unroll
                for (int w = 0; w < W_; ++w)
                    acc = fmaf(h[w], wmd[v * W_ + w], acc);
                h2[v] = selu_f(acc);
            }
            #pragma unroll
            for (int w = 0; w < W_; ++w) h[w] = h2[w];
        }

        // final: out[b,g] = sum_w h[w] * Wf[g,w] + bf[g]
        float acc = bf[g];
        #pragma unroll
        for (int w = 0; w < W_; ++w)
            acc = fmaf(h[w], Wf[g * W_ + w], acc);
        res[gi] = acc;
    }

    // Coalesced-line epilogue: each thread writes one full 64B cache line.
    // (b*G + g0)*4 is 64B-aligned: 20000*4 = 80000 = 1250*64, g0 % 16 == 0.
    float4* o = (float4*)(out + (size_t)b * G_ + g0);
    #pragma unroll
    for (int i = 0; i < GPB / 4; ++i)
        o[i] = make_float4(res[4 * i], res[4 * i + 1],
                           res[4 * i + 2], res[4 * i + 3]);
}

extern "C" void kernel_launch(void* const* d_in, const int* in_sizes, int n_in,
                              void* d_out, int out_size, void* d_ws, size_t ws_size,
                              hipStream_t stream) {
    const float* feat   = (const float*)d_in[0];
    const int*   tf_idx = (const int*)  d_in[1];
    const float* W1     = (const float*)d_in[2];
    const float* b1     = (const float*)d_in[3];
    const float* Wm     = (const float*)d_in[4];
    const float* bm     = (const float*)d_in[5];
    const float* Wf     = (const float*)d_in[6];
    const float* bf     = (const float*)d_in[7];
    float* out = (float*)d_out;

    const size_t featT_bytes = (size_t)T_ * B_ * sizeof(float);
    if (ws_size >= featT_bytes) {
        float* featT = (float*)d_ws;
        dim3 tgrid((T_ + 31) / 32, (B_ + 31) / 32);
        dim3 tblock(32, 8);
        hipLaunchKernelGGL(transpose_feat, tgrid, tblock, 0, stream, feat, featT);
        hipLaunchKernelGGL((decoder_kernel<true>), dim3(G_ / GPB), dim3(B_), 0,
                           stream, featT, tf_idx, W1, b1, Wm, bm, Wf, bf, out);
    } else {
        hipLaunchKernelGGL((decoder_kernel<false>), dim3(G_ / GPB), dim3(B_), 0,
                           stream, feat, tf_idx, W1, b1, Wm, bm, Wf, bf, out);
    }
}

// Round 2
// 86.733 us; speedup vs baseline: 1.2655x; 1.2655x over previous
//
#include <hip/hip_runtime.h>

#define G_ 20000
#define W_ 8
#define K_ 16
#define T_ 1500
#define B_ 256
#define D_ 2
#define GPB 4    // groups per block; grid = 20000/4 = 5000 blocks -> 20000 waves
                 // (round 1: GPB=16 -> only 5000 waves total, occupancy-capped at 46%)

__device__ __forceinline__ float selu_f(float x) {
    const float scale = 1.0507009873554805f;
    const float alpha = 1.6732632423543772f;
    float neg = scale * alpha * (__expf(x) - 1.0f);
    return x > 0.0f ? scale * x : neg;
}

// feat (B,T) -> featT (T,B) so the main kernel's gather is lane-coalesced.
__global__ void transpose_feat(const float* __restrict__ feat,
                               float* __restrict__ featT) {
    __shared__ float tile[32][33];
    int t0 = blockIdx.x * 32;
    int b0 = blockIdx.y * 32;
    int tx = threadIdx.x, ty = threadIdx.y;  // block (32,8)
    #pragma unroll
    for (int i = 0; i < 32; i += 8) {
        int bb = b0 + ty + i, tt = t0 + tx;
        if (bb < B_ && tt < T_) tile[ty + i][tx] = feat[bb * T_ + tt];
    }
    __syncthreads();
    #pragma unroll
    for (int i = 0; i < 32; i += 8) {
        int tt = t0 + ty + i, bb = b0 + tx;
        if (tt < T_ && bb < B_) featT[tt * B_ + bb] = tile[tx][ty + i];
    }
}

// One block = 256 threads (thread = batch row b), GPB consecutive groups.
// Weight/index addresses are block-uniform -> s_load broadcast; per-thread
// state stays in ~45 VGPRs -> occupancy HW-capped (8 waves/SIMD).
template<bool TRANSPOSED>
__global__ __launch_bounds__(256) void decoder_kernel(
    const float* __restrict__ featsrc,   // featT (T,B) if TRANSPOSED else feat (B,T)
    const int*   __restrict__ tf_idx,    // (G,K)
    const float* __restrict__ W1,        // (G,W,K)
    const float* __restrict__ b1,        // (G,W)
    const float* __restrict__ Wm,        // (D,G,W,W)
    const float* __restrict__ bm,        // (D,G,W)
    const float* __restrict__ Wf,        // (G,W)
    const float* __restrict__ bf,        // (G,)
    float* __restrict__ out)             // (B,G)
{
    const int b  = threadIdx.x;
    const int g0 = blockIdx.x * GPB;
    float res[GPB];

    #pragma unroll
    for (int gi = 0; gi < GPB; ++gi) {
        const int g = g0 + gi;

        // gather xg[b, g, k] = features[b, tf_idx[g,k]]
        float xg[K_];
        #pragma unroll
        for (int k = 0; k < K_; ++k) {
            int t = tf_idx[g * K_ + k];                       // uniform -> s_load
            xg[k] = TRANSPOSED ? featsrc[t * B_ + b]          // coalesced
                               : featsrc[b * T_ + t];         // fallback
        }

        // layer 1: h[w] = selu(sum_k xg[k] * W1[g,w,k] + b1[g,w])
        float h[W_];
        #pragma unroll
        for (int w = 0; w < W_; ++w) {
            float acc = b1[g * W_ + w];
            #pragma unroll
            for (int k = 0; k < K_; ++k)
                acc = fmaf(xg[k], W1[(g * W_ + w) * K_ + k], acc);
            h[w] = selu_f(acc);
        }

        // D mid layers: h[v] = selu(sum_w h[w] * Wm[d,g,v,w] + bm[d,g,v])
        #pragma unroll
        for (int d = 0; d < D_; ++d) {
            const float* wmd = Wm + ((size_t)d * G_ + g) * (W_ * W_);
            const float* bmd = bm + ((size_t)d * G_ + g) * W_;
            float h2[W_];
            #pragma unroll
            for (int v = 0; v < W_; ++v) {
                float acc = bmd[v];
                #pragma unroll
                for (int w = 0; w < W_; ++w)
                    acc = fmaf(h[w], wmd[v * W_ + w], acc);
                h2[v] = selu_f(acc);
            }
            #pragma unroll
            for (int w = 0; w < W_; ++w) h[w] = h2[w];
        }

        // final: out[b,g] = sum_w h[w] * Wf[g,w] + bf[g]
        float acc = bf[g];
        #pragma unroll
        for (int w = 0; w < W_; ++w)
            acc = fmaf(h[w], Wf[g * W_ + w], acc);
        res[gi] = acc;
    }

    // Coalesced epilogue: one float4 per thread, 16B-aligned
    // ((b*20000 + g0)*4 % 16 == 0 since g0 % 4 == 0).
    float4* o = (float4*)(out + (size_t)b * G_ + g0);
    o[0] = make_float4(res[0], res[1], res[2], res[3]);
}

extern "C" void kernel_launch(void* const* d_in, const int* in_sizes, int n_in,
                              void* d_out, int out_size, void* d_ws, size_t ws_size,
                              hipStream_t stream) {
    const float* feat   = (const float*)d_in[0];
    const int*   tf_idx = (const int*)  d_in[1];
    const float* W1     = (const float*)d_in[2];
    const float* b1     = (const float*)d_in[3];
    const float* Wm     = (const float*)d_in[4];
    const float* bm     = (const float*)d_in[5];
    const float* Wf     = (const float*)d_in[6];
    const float* bf     = (const float*)d_in[7];
    float* out = (float*)d_out;

    const size_t featT_bytes = (size_t)T_ * B_ * sizeof(float);
    if (ws_size >= featT_bytes) {
        float* featT = (float*)d_ws;
        dim3 tgrid((T_ + 31) / 32, (B_ + 31) / 32);
        dim3 tblock(32, 8);
        hipLaunchKernelGGL(transpose_feat, tgrid, tblock, 0, stream, feat, featT);
        hipLaunchKernelGGL((decoder_kernel<true>), dim3(G_ / GPB), dim3(B_), 0,
                           stream, featT, tf_idx, W1, b1, Wm, bm, Wf, bf, out);
    } else {
        hipLaunchKernelGGL((decoder_kernel<false>), dim3(G_ / GPB), dim3(B_), 0,
                           stream, feat, tf_idx, W1, b1, Wm, bm, Wf, bf, out);
    }
}